// Round 2
// baseline (2640.399 us; speedup 1.0000x reference)
//
#include <hip/hip_runtime.h>
#include <hip/hip_bf16.h>
#include <math.h>

#define N_NODES 100000
#define N_EDGES 3200000
#define N_GRAPHS 16
#define C 64
#define L 6
#define H 32
#define EPS 1e-5f

static const int SCAN_BLOCKS = (N_NODES + 1023) / 1024;  // 98

__device__ __forceinline__ float gelu_exact(float x) {
    return 0.5f * x * (1.0f + erff(x * 0.70710678118654752440f));
}

__device__ __forceinline__ float wave_sum64(float v) {
#pragma unroll
    for (int m = 32; m >= 1; m >>= 1) v += __shfl_xor(v, m, 64);
    return v;
}

// sum over aligned 32-lane subgroup (masks <=16 stay inside the subgroup)
__device__ __forceinline__ float sum32(float v) {
#pragma unroll
    for (int m = 16; m >= 1; m >>= 1) v += __shfl_xor(v, m, 64);
    return v;
}

// ---------------- CSR build ----------------

__global__ void k_count(const int* __restrict__ dst, int* __restrict__ degc) {
    int i = blockIdx.x * blockDim.x + threadIdx.x;
    int stride = gridDim.x * blockDim.x;
    for (int e = i; e < N_EDGES; e += stride) atomicAdd(&degc[dst[e]], 1);
}

__global__ __launch_bounds__(256) void k_scan1(const int* __restrict__ degc,
                                               int* __restrict__ scanned,
                                               int* __restrict__ bsum) {
    __shared__ int sc[2][256];
    int tid = threadIdx.x;
    int base = blockIdx.x * 1024 + tid * 4;
    int c0 = (base + 0 < N_NODES) ? degc[base + 0] : 0;
    int c1 = (base + 1 < N_NODES) ? degc[base + 1] : 0;
    int c2 = (base + 2 < N_NODES) ? degc[base + 2] : 0;
    int c3 = (base + 3 < N_NODES) ? degc[base + 3] : 0;
    int p0 = c0, p1 = p0 + c1, p2 = p1 + c2, p3 = p2 + c3;
    sc[0][tid] = p3;
    __syncthreads();
    int pb = 0;
    for (int offd = 1; offd < 256; offd <<= 1) {
        int v = sc[pb][tid];
        if (tid >= offd) v += sc[pb][tid - offd];
        sc[pb ^ 1][tid] = v;
        __syncthreads();
        pb ^= 1;
    }
    int incl = sc[pb][tid];
    int exth = incl - p3;  // exclusive offset of this thread within block
    if (base + 0 < N_NODES) scanned[base + 0] = exth + p0;
    if (base + 1 < N_NODES) scanned[base + 1] = exth + p1;
    if (base + 2 < N_NODES) scanned[base + 2] = exth + p2;
    if (base + 3 < N_NODES) scanned[base + 3] = exth + p3;
    if (tid == 255) bsum[blockIdx.x] = incl;
}

__global__ void k_scan2(const int* __restrict__ bsum, int* __restrict__ boff,
                        int* __restrict__ rowst) {
    int run = 0;
    for (int b = 0; b < SCAN_BLOCKS; ++b) { boff[b] = run; run += bsum[b]; }
    rowst[N_NODES] = run;  // == N_EDGES
}

__global__ void k_scan3(const int* __restrict__ degc, const int* __restrict__ scanned,
                        const int* __restrict__ boff, int* __restrict__ rowst) {
    int i = blockIdx.x * blockDim.x + threadIdx.x;
    if (i < N_NODES) rowst[i] = boff[i >> 10] + scanned[i] - degc[i];
}

__global__ void k_fill(const int* __restrict__ src, const int* __restrict__ dst,
                       const int* __restrict__ rowst, int* __restrict__ cursor,
                       int* __restrict__ esrc) {
    int i = blockIdx.x * blockDim.x + threadIdx.x;
    int stride = gridDim.x * blockDim.x;
    for (int e = i; e < N_EDGES; e += stride) {
        int d = dst[e];
        int pos = atomicAdd(&cursor[d], 1);
        esrc[rowst[d] + pos] = src[e];
    }
}

// ---------------- per-layer: mean aggregation (gather via CSR) ----------------

__global__ __launch_bounds__(256) void k_agg(const float* __restrict__ h,
                                             const int* __restrict__ rowst,
                                             const int* __restrict__ esrc,
                                             float* __restrict__ agg) {
    int wave = threadIdx.x >> 6, lane = threadIdx.x & 63;
    int n = blockIdx.x * 4 + wave;
    if (n >= N_NODES) return;
    int s0 = rowst[n], s1 = rowst[n + 1];
    float acc = 0.f;
    for (int j = s0; j < s1; ++j) {
        int s = esrc[j];
        acc += h[s * C + lane];
    }
    int cnt = s1 - s0;
    float inv = (cnt > 0) ? 1.0f / (float)cnt : 1.0f;
    agg[n * C + lane] = acc * inv;
}

// ---------------- per-layer: fused GEMM+GELU+LN+residual ----------------
// Block = 4 waves. Waves (0,1) -> node grp*2, waves (2,3) -> node grp*2+1.
// Even wave: agg @ Wl (weights col in regs). Odd wave: h @ Wr. Combine in LDS.

__global__ __launch_bounds__(256) void k_sage(const float* __restrict__ h,
                                              const float* __restrict__ agg,
                                              const float* __restrict__ Wl,
                                              const float* __restrict__ bl,
                                              const float* __restrict__ Wr,
                                              const float* __restrict__ gn,
                                              const float* __restrict__ bn,
                                              float* __restrict__ hout) {
    __shared__ float src_s[4][C];
    __shared__ float part_s[2][C];
    int lane = threadIdx.x & 63;
    int wave = threadIdx.x >> 6;
    int which = wave & 1;  // 0: Wl*agg (+epilogue), 1: Wr*h
    int sub = wave >> 1;   // node sub-index within group
    const float* W = which ? Wr : Wl;
    float wreg[C];
#pragma unroll
    for (int j = 0; j < C; ++j) wreg[j] = W[j * C + lane];  // column `lane`
    float blc = bl[lane], gc = gn[lane], bc = bn[lane];

    for (int grp = blockIdx.x; grp < N_NODES / 2; grp += gridDim.x) {
        int n = grp * 2 + sub;
        const float* srcrow = which ? (h + (size_t)n * C) : (agg + (size_t)n * C);
        src_s[wave][lane] = srcrow[lane];
        // wave-private LDS row; same-wave write->read, no block barrier needed
        float acc = 0.f;
        const float4* s4 = (const float4*)src_s[wave];
#pragma unroll
        for (int k4 = 0; k4 < C / 4; ++k4) {
            float4 a = s4[k4];
            acc += a.x * wreg[4 * k4 + 0] + a.y * wreg[4 * k4 + 1] +
                   a.z * wreg[4 * k4 + 2] + a.w * wreg[4 * k4 + 3];
        }
        if (which) part_s[sub][lane] = acc;
        __syncthreads();
        if (!which) {
            float f = acc + part_s[sub][lane] + blc;
            f = gelu_exact(f);
            float mu = wave_sum64(f) * (1.0f / C);
            float d = f - mu;
            float var = wave_sum64(d * d) * (1.0f / C);
            float y = d * rsqrtf(var + EPS) * gc + bc;
            hout[(size_t)n * C + lane] = y + src_s[2 * sub + 1][lane];  // residual
        }
        __syncthreads();
    }
}

// ---------------- pooling (segment_max) ----------------

__global__ __launch_bounds__(256) void k_pool_partial(const float* __restrict__ h,
                                                      const int* __restrict__ batch,
                                                      float* __restrict__ partial) {
    __shared__ float pp[4][N_GRAPHS][C];
    int lane = threadIdx.x & 63, wave = threadIdx.x >> 6;
#pragma unroll
    for (int g = 0; g < N_GRAPHS; ++g) pp[wave][g][lane] = -INFINITY;
    int chunk = (N_NODES + gridDim.x - 1) / gridDim.x;
    int start = blockIdx.x * chunk;
    int end = min(start + chunk, N_NODES);
    for (int n = start + wave; n < end; n += 4) {
        int g = batch[n];
        float v = h[(size_t)n * C + lane];
        pp[wave][g][lane] = fmaxf(pp[wave][g][lane], v);
    }
    __syncthreads();
    for (int g = wave * 4; g < wave * 4 + 4; ++g) {
        float m = fmaxf(fmaxf(pp[0][g][lane], pp[1][g][lane]),
                        fmaxf(pp[2][g][lane], pp[3][g][lane]));
        partial[(size_t)blockIdx.x * (N_GRAPHS * C) + g * C + lane] = m;
    }
}

__global__ void k_pool_final(const float* __restrict__ partial, float* __restrict__ pooled) {
    int t = threadIdx.x;  // 1024 threads = 16*64
    float m = -INFINITY;
    for (int b = 0; b < 128; ++b) m = fmaxf(m, partial[b * (N_GRAPHS * C) + t]);
    pooled[t] = m;
}

// ---------------- MLP head ----------------

__global__ __launch_bounds__(512) void k_head(const float* __restrict__ pooled,
                                              const float* __restrict__ W0,
                                              const float* __restrict__ b0,
                                              const float* __restrict__ g0,
                                              const float* __restrict__ bn0,
                                              const float* __restrict__ W,
                                              const float* __restrict__ bb,
                                              const float* __restrict__ gg,
                                              const float* __restrict__ bnn,
                                              const float* __restrict__ hW,
                                              const float* __restrict__ hb,
                                              float* __restrict__ out) {
    __shared__ float ps[N_GRAPHS][C];
    __shared__ float zs[N_GRAPHS][H];
    int t = threadIdx.x;
    for (int i = t; i < N_GRAPHS * C; i += 512) ps[i >> 6][i & 63] = pooled[i];
    __syncthreads();
    int g = t >> 5, j = t & 31;
    float acc = b0[j];
#pragma unroll 8
    for (int k = 0; k < C; ++k) acc += ps[g][k] * W0[k * H + j];
    acc = gelu_exact(acc);
    float mu = sum32(acc) * (1.0f / H);
    float d = acc - mu;
    float var = sum32(d * d) * (1.0f / H);
    float z = d * rsqrtf(var + EPS) * g0[j] + bn0[j];
    zs[g][j] = z;
    __syncthreads();
    for (int i = 0; i < 3; ++i) {
        float a = bb[i * H + j];
#pragma unroll 8
        for (int k = 0; k < H; ++k) a += zs[g][k] * W[i * H * H + k * H + j];
        a = gelu_exact(a);
        float mu2 = sum32(a) * (1.0f / H);
        float d2 = a - mu2;
        float v2 = sum32(d2 * d2) * (1.0f / H);
        float tt = d2 * rsqrtf(v2 + EPS) * gg[i * H + j] + bnn[i * H + j];
        float zn = tt + zs[g][j];
        __syncthreads();
        zs[g][j] = zn;
        __syncthreads();
    }
    float hv = zs[g][j] * hW[j];
    hv = sum32(hv);
    if (j == 0) out[g] = hv + hb[0];
}

// ---------------- launch ----------------

extern "C" void kernel_launch(void* const* d_in, const int* in_sizes, int n_in,
                              void* d_out, int out_size, void* d_ws, size_t ws_size,
                              hipStream_t stream) {
    const float* x    = (const float*)d_in[0];
    const int* edge   = (const int*)d_in[1];
    const int* batch  = (const int*)d_in[2];
    const float* sWl  = (const float*)d_in[3];
    const float* sbl  = (const float*)d_in[4];
    const float* sWr  = (const float*)d_in[5];
    const float* sg   = (const float*)d_in[6];
    const float* sb   = (const float*)d_in[7];
    const float* W0   = (const float*)d_in[8];
    const float* b0   = (const float*)d_in[9];
    const float* g0   = (const float*)d_in[10];
    const float* bn0  = (const float*)d_in[11];
    const float* mW   = (const float*)d_in[12];
    const float* mb   = (const float*)d_in[13];
    const float* mg   = (const float*)d_in[14];
    const float* mbn  = (const float*)d_in[15];
    const float* hW   = (const float*)d_in[16];
    const float* hb   = (const float*)d_in[17];
    float* out = (float*)d_out;

    const int* esrc_in = edge;            // edge_index[0]
    const int* edst_in = edge + N_EDGES;  // edge_index[1]

    char* ws = (char*)d_ws;
    size_t off = 0;
    auto alloc = [&](size_t bytes) {
        void* p = ws + off;
        off = (off + bytes + 1023) & ~(size_t)1023;
        return p;
    };
    float* h      = (float*)alloc((size_t)N_NODES * C * 4);
    float* agg    = (float*)alloc((size_t)N_NODES * C * 4);
    int* degc     = (int*)alloc((size_t)N_NODES * 4);
    int* scanned  = (int*)alloc((size_t)N_NODES * 4);
    int* rowst    = (int*)alloc((size_t)(N_NODES + 1) * 4);
    int* cursor   = (int*)alloc((size_t)N_NODES * 4);
    int* esrc     = (int*)alloc((size_t)N_EDGES * 4);
    int* bsum     = (int*)alloc(128 * 4);
    int* boff     = (int*)alloc(128 * 4);
    float* part   = (float*)alloc((size_t)128 * N_GRAPHS * C * 4);
    float* pooled = (float*)alloc((size_t)N_GRAPHS * C * 4);
    (void)ws_size;

    hipMemsetAsync(degc, 0, (size_t)N_NODES * 4, stream);
    hipMemsetAsync(cursor, 0, (size_t)N_NODES * 4, stream);
    hipMemcpyAsync(h, x, (size_t)N_NODES * C * 4, hipMemcpyDeviceToDevice, stream);

    k_count<<<2048, 256, 0, stream>>>(edst_in, degc);
    k_scan1<<<SCAN_BLOCKS, 256, 0, stream>>>(degc, scanned, bsum);
    k_scan2<<<1, 1, 0, stream>>>(bsum, boff, rowst);
    k_scan3<<<(N_NODES + 255) / 256, 256, 0, stream>>>(degc, scanned, boff, rowst);
    k_fill<<<2048, 256, 0, stream>>>(esrc_in, edst_in, rowst, cursor, esrc);

    for (int i = 0; i < L; ++i) {
        k_agg<<<N_NODES / 4, 256, 0, stream>>>(h, rowst, esrc, agg);
        k_sage<<<2048, 256, 0, stream>>>(h, agg, sWl + (size_t)i * C * C, sbl + (size_t)i * C,
                                         sWr + (size_t)i * C * C, sg + (size_t)i * C,
                                         sb + (size_t)i * C, h);
    }

    k_pool_partial<<<128, 256, 0, stream>>>(h, batch, part);
    k_pool_final<<<1, 1024, 0, stream>>>(part, pooled);
    k_head<<<1, 512, 0, stream>>>(pooled, W0, b0, g0, bn0, mW, mb, mg, mbn, hW, hb, out);
}

// Round 3
// 1469.125 us; speedup vs baseline: 1.7973x; 1.7973x over previous
//
#include <hip/hip_runtime.h>
#include <hip/hip_bf16.h>
#include <math.h>

#define N_NODES 100000
#define N_EDGES 3200000
#define N_GRAPHS 16
#define C 64
#define L 6
#define H 32
#define EPS 1e-5f

static const int SCAN_BLOCKS = (N_NODES + 1023) / 1024;  // 98

__device__ __forceinline__ float gelu_exact(float x) {
    return 0.5f * x * (1.0f + erff(x * 0.70710678118654752440f));
}

__device__ __forceinline__ float wave_sum64(float v) {
#pragma unroll
    for (int m = 32; m >= 1; m >>= 1) v += __shfl_xor(v, m, 64);
    return v;
}

// sum over aligned 32-lane subgroup (masks <=16 stay inside the subgroup)
__device__ __forceinline__ float sum32(float v) {
#pragma unroll
    for (int m = 16; m >= 1; m >>= 1) v += __shfl_xor(v, m, 64);
    return v;
}

// ---------------- CSR build ----------------
// Pass 1: count in-degree AND record each edge's position within its dst bucket
// (removes the atomic from the fill pass).

__global__ void k_count(const int* __restrict__ dst, int* __restrict__ degc,
                        int* __restrict__ epos) {
    int i = blockIdx.x * blockDim.x + threadIdx.x;
    int stride = gridDim.x * blockDim.x;
    for (int e = i; e < N_EDGES; e += stride) {
        int pos = atomicAdd(&degc[dst[e]], 1);
        epos[e] = pos;
    }
}

__global__ __launch_bounds__(256) void k_scan1(const int* __restrict__ degc,
                                               int* __restrict__ scanned,
                                               int* __restrict__ bsum) {
    __shared__ int sc[2][256];
    int tid = threadIdx.x;
    int base = blockIdx.x * 1024 + tid * 4;
    int c0 = (base + 0 < N_NODES) ? degc[base + 0] : 0;
    int c1 = (base + 1 < N_NODES) ? degc[base + 1] : 0;
    int c2 = (base + 2 < N_NODES) ? degc[base + 2] : 0;
    int c3 = (base + 3 < N_NODES) ? degc[base + 3] : 0;
    int p0 = c0, p1 = p0 + c1, p2 = p1 + c2, p3 = p2 + c3;
    sc[0][tid] = p3;
    __syncthreads();
    int pb = 0;
    for (int offd = 1; offd < 256; offd <<= 1) {
        int v = sc[pb][tid];
        if (tid >= offd) v += sc[pb][tid - offd];
        sc[pb ^ 1][tid] = v;
        __syncthreads();
        pb ^= 1;
    }
    int incl = sc[pb][tid];
    int exth = incl - p3;
    if (base + 0 < N_NODES) scanned[base + 0] = exth + p0;
    if (base + 1 < N_NODES) scanned[base + 1] = exth + p1;
    if (base + 2 < N_NODES) scanned[base + 2] = exth + p2;
    if (base + 3 < N_NODES) scanned[base + 3] = exth + p3;
    if (tid == 255) bsum[blockIdx.x] = incl;
}

__global__ void k_scan2(const int* __restrict__ bsum, int* __restrict__ boff,
                        int* __restrict__ rowst) {
    int run = 0;
    for (int b = 0; b < SCAN_BLOCKS; ++b) { boff[b] = run; run += bsum[b]; }
    rowst[N_NODES] = run;  // == N_EDGES
}

__global__ void k_scan3(const int* __restrict__ degc, const int* __restrict__ scanned,
                        const int* __restrict__ boff, int* __restrict__ rowst) {
    int i = blockIdx.x * blockDim.x + threadIdx.x;
    if (i < N_NODES) rowst[i] = boff[i >> 10] + scanned[i] - degc[i];
}

__global__ void k_fill(const int* __restrict__ src, const int* __restrict__ dst,
                       const int* __restrict__ rowst, const int* __restrict__ epos,
                       int* __restrict__ esrc) {
    int i = blockIdx.x * blockDim.x + threadIdx.x;
    int stride = gridDim.x * blockDim.x;
    for (int e = i; e < N_EDGES; e += stride) {
        int d = dst[e];
        esrc[rowst[d] + epos[e]] = src[e];
    }
}

// ---------------- per-layer: mean aggregation (gather via CSR) ----------------
// One wave per node. float4 lanes: lane = (edge sub-index lane>>4) x (channel
// quad lane&15). 4 edges per vmem instruction, 16 edges in flight per
// iteration (2 accumulators), no shuffles in the hot loop.

__global__ __launch_bounds__(256) void k_agg(const float* __restrict__ h,
                                             const int* __restrict__ rowst,
                                             const int* __restrict__ esrc,
                                             float* __restrict__ agg) {
    const float4* __restrict__ h4 = (const float4*)h;
    int wave = threadIdx.x >> 6, lane = threadIdx.x & 63;
    int n = blockIdx.x * 4 + wave;
    if (n >= N_NODES) return;
    int s0 = rowst[n], s1 = rowst[n + 1];
    int esub = lane >> 4;    // 0..3 edge sub-index
    int cq = lane & 15;      // channel quad
    float4 accA = make_float4(0.f, 0.f, 0.f, 0.f);
    float4 accB = make_float4(0.f, 0.f, 0.f, 0.f);
    int j = s0;
    for (; j + 16 <= s1; j += 16) {
        int sA = esrc[j + 0 + esub];
        int sB = esrc[j + 4 + esub];
        int sC = esrc[j + 8 + esub];
        int sD = esrc[j + 12 + esub];
        float4 a = h4[sA * 16 + cq];
        float4 b = h4[sB * 16 + cq];
        float4 c = h4[sC * 16 + cq];
        float4 d = h4[sD * 16 + cq];
        accA.x += a.x; accA.y += a.y; accA.z += a.z; accA.w += a.w;
        accB.x += b.x; accB.y += b.y; accB.z += b.z; accB.w += b.w;
        accA.x += c.x; accA.y += c.y; accA.z += c.z; accA.w += c.w;
        accB.x += d.x; accB.y += d.y; accB.z += d.z; accB.w += d.w;
    }
    for (; j + 4 <= s1; j += 4) {
        int s = esrc[j + esub];
        float4 a = h4[s * 16 + cq];
        accA.x += a.x; accA.y += a.y; accA.z += a.z; accA.w += a.w;
    }
    if (j < s1) {  // 1..3 leftover edges, predicated
        int jj = j + esub;
        bool v = jj < s1;
        int s = v ? esrc[jj] : 0;
        float4 a = h4[s * 16 + cq];
        accB.x += v ? a.x : 0.f; accB.y += v ? a.y : 0.f;
        accB.z += v ? a.z : 0.f; accB.w += v ? a.w : 0.f;
    }
    accA.x += accB.x; accA.y += accB.y; accA.z += accB.z; accA.w += accB.w;
    // reduce across the 4 edge sub-groups (lanes differing in bits 4,5)
#pragma unroll
    for (int m = 16; m <= 32; m <<= 1) {
        accA.x += __shfl_xor(accA.x, m, 64);
        accA.y += __shfl_xor(accA.y, m, 64);
        accA.z += __shfl_xor(accA.z, m, 64);
        accA.w += __shfl_xor(accA.w, m, 64);
    }
    int cnt = s1 - s0;
    float inv = 1.0f / (float)max(cnt, 1);
    if (lane < 16) {
        float4 r = make_float4(accA.x * inv, accA.y * inv, accA.z * inv, accA.w * inv);
        ((float4*)agg)[(size_t)n * 16 + lane] = r;
    }
}

// ---------------- per-layer: fused GEMM+GELU+LN+residual ----------------
// One wave per node, BOTH GEMMs in-wave (Wl+Wr columns in 128 VGPRs),
// wave-private LDS rows, no block barriers. Persistent grid amortizes
// the weight-register load.

__global__ __launch_bounds__(256) void k_sage(const float* __restrict__ h,
                                              const float* __restrict__ agg,
                                              const float* __restrict__ Wl,
                                              const float* __restrict__ bl,
                                              const float* __restrict__ Wr,
                                              const float* __restrict__ gn,
                                              const float* __restrict__ bn,
                                              float* __restrict__ hout) {
    __shared__ float rowA[4][C];
    __shared__ float rowH[4][C];
    int lane = threadIdx.x & 63;
    int wave = threadIdx.x >> 6;
    float wl[C], wr[C];
#pragma unroll
    for (int j = 0; j < C; ++j) wl[j] = Wl[j * C + lane];  // column `lane`
#pragma unroll
    for (int j = 0; j < C; ++j) wr[j] = Wr[j * C + lane];
    float blc = bl[lane], gc = gn[lane], bc = bn[lane];

    const float4* a4 = (const float4*)rowA[wave];
    const float4* h4s = (const float4*)rowH[wave];
    for (int n = blockIdx.x * 4 + wave; n < N_NODES; n += 2048 * 4) {
        float av = agg[(size_t)n * C + lane];
        float hv = h[(size_t)n * C + lane];
        rowA[wave][lane] = av;
        rowH[wave][lane] = hv;
        float acc = blc;
#pragma unroll
        for (int k4 = 0; k4 < C / 4; ++k4) {
            float4 a = a4[k4];
            float4 b = h4s[k4];
            acc += a.x * wl[4 * k4 + 0] + a.y * wl[4 * k4 + 1] +
                   a.z * wl[4 * k4 + 2] + a.w * wl[4 * k4 + 3];
            acc += b.x * wr[4 * k4 + 0] + b.y * wr[4 * k4 + 1] +
                   b.z * wr[4 * k4 + 2] + b.w * wr[4 * k4 + 3];
        }
        float f = gelu_exact(acc);
        float mu = wave_sum64(f) * (1.0f / C);
        float d = f - mu;
        float var = wave_sum64(d * d) * (1.0f / C);
        float y = d * rsqrtf(var + EPS) * gc + bc;
        hout[(size_t)n * C + lane] = y + hv;  // residual
    }
}

// ---------------- pooling (segment_max) ----------------

__global__ __launch_bounds__(256) void k_pool_partial(const float* __restrict__ h,
                                                      const int* __restrict__ batch,
                                                      float* __restrict__ partial) {
    __shared__ float pp[4][N_GRAPHS][C];
    int lane = threadIdx.x & 63, wave = threadIdx.x >> 6;
#pragma unroll
    for (int g = 0; g < N_GRAPHS; ++g) pp[wave][g][lane] = -INFINITY;
    int chunk = (N_NODES + gridDim.x - 1) / gridDim.x;
    int start = blockIdx.x * chunk;
    int end = min(start + chunk, N_NODES);
    for (int n = start + wave; n < end; n += 4) {
        int g = batch[n];
        float v = h[(size_t)n * C + lane];
        pp[wave][g][lane] = fmaxf(pp[wave][g][lane], v);
    }
    __syncthreads();
    for (int g = wave * 4; g < wave * 4 + 4; ++g) {
        float m = fmaxf(fmaxf(pp[0][g][lane], pp[1][g][lane]),
                        fmaxf(pp[2][g][lane], pp[3][g][lane]));
        partial[(size_t)blockIdx.x * (N_GRAPHS * C) + g * C + lane] = m;
    }
}

__global__ void k_pool_final(const float* __restrict__ partial, float* __restrict__ pooled) {
    int t = threadIdx.x;  // 1024 threads = 16*64
    float m = -INFINITY;
    for (int b = 0; b < 128; ++b) m = fmaxf(m, partial[b * (N_GRAPHS * C) + t]);
    pooled[t] = m;
}

// ---------------- MLP head ----------------

__global__ __launch_bounds__(512) void k_head(const float* __restrict__ pooled,
                                              const float* __restrict__ W0,
                                              const float* __restrict__ b0,
                                              const float* __restrict__ g0,
                                              const float* __restrict__ bn0,
                                              const float* __restrict__ W,
                                              const float* __restrict__ bb,
                                              const float* __restrict__ gg,
                                              const float* __restrict__ bnn,
                                              const float* __restrict__ hW,
                                              const float* __restrict__ hb,
                                              float* __restrict__ out) {
    __shared__ float ps[N_GRAPHS][C];
    __shared__ float zs[N_GRAPHS][H];
    int t = threadIdx.x;
    for (int i = t; i < N_GRAPHS * C; i += 512) ps[i >> 6][i & 63] = pooled[i];
    __syncthreads();
    int g = t >> 5, j = t & 31;
    float acc = b0[j];
#pragma unroll 8
    for (int k = 0; k < C; ++k) acc += ps[g][k] * W0[k * H + j];
    acc = gelu_exact(acc);
    float mu = sum32(acc) * (1.0f / H);
    float d = acc - mu;
    float var = sum32(d * d) * (1.0f / H);
    float z = d * rsqrtf(var + EPS) * g0[j] + bn0[j];
    zs[g][j] = z;
    __syncthreads();
    for (int i = 0; i < 3; ++i) {
        float a = bb[i * H + j];
#pragma unroll 8
        for (int k = 0; k < H; ++k) a += zs[g][k] * W[i * H * H + k * H + j];
        a = gelu_exact(a);
        float mu2 = sum32(a) * (1.0f / H);
        float d2 = a - mu2;
        float v2 = sum32(d2 * d2) * (1.0f / H);
        float tt = d2 * rsqrtf(v2 + EPS) * gg[i * H + j] + bnn[i * H + j];
        float zn = tt + zs[g][j];
        __syncthreads();
        zs[g][j] = zn;
        __syncthreads();
    }
    float hv = zs[g][j] * hW[j];
    hv = sum32(hv);
    if (j == 0) out[g] = hv + hb[0];
}

// ---------------- launch ----------------

extern "C" void kernel_launch(void* const* d_in, const int* in_sizes, int n_in,
                              void* d_out, int out_size, void* d_ws, size_t ws_size,
                              hipStream_t stream) {
    const float* x    = (const float*)d_in[0];
    const int* edge   = (const int*)d_in[1];
    const int* batch  = (const int*)d_in[2];
    const float* sWl  = (const float*)d_in[3];
    const float* sbl  = (const float*)d_in[4];
    const float* sWr  = (const float*)d_in[5];
    const float* sg   = (const float*)d_in[6];
    const float* sb   = (const float*)d_in[7];
    const float* W0   = (const float*)d_in[8];
    const float* b0   = (const float*)d_in[9];
    const float* g0   = (const float*)d_in[10];
    const float* bn0  = (const float*)d_in[11];
    const float* mW   = (const float*)d_in[12];
    const float* mb   = (const float*)d_in[13];
    const float* mg   = (const float*)d_in[14];
    const float* mbn  = (const float*)d_in[15];
    const float* hW   = (const float*)d_in[16];
    const float* hb   = (const float*)d_in[17];
    float* out = (float*)d_out;

    const int* esrc_in = edge;            // edge_index[0]
    const int* edst_in = edge + N_EDGES;  // edge_index[1]

    char* ws = (char*)d_ws;
    size_t off = 0;
    auto alloc = [&](size_t bytes) {
        void* p = ws + off;
        off = (off + bytes + 1023) & ~(size_t)1023;
        return p;
    };
    float* h      = (float*)alloc((size_t)N_NODES * C * 4);
    float* agg    = (float*)alloc((size_t)N_NODES * C * 4);
    int* degc     = (int*)alloc((size_t)N_NODES * 4);
    int* scanned  = (int*)alloc((size_t)N_NODES * 4);
    int* rowst    = (int*)alloc((size_t)(N_NODES + 1) * 4);
    int* esrc     = (int*)alloc((size_t)N_EDGES * 4);
    int* epos     = (int*)alloc((size_t)N_EDGES * 4);
    int* bsum     = (int*)alloc(128 * 4);
    int* boff     = (int*)alloc(128 * 4);
    float* part   = (float*)alloc((size_t)128 * N_GRAPHS * C * 4);
    float* pooled = (float*)alloc((size_t)N_GRAPHS * C * 4);
    (void)ws_size;

    hipMemsetAsync(degc, 0, (size_t)N_NODES * 4, stream);
    hipMemcpyAsync(h, x, (size_t)N_NODES * C * 4, hipMemcpyDeviceToDevice, stream);

    k_count<<<2048, 256, 0, stream>>>(edst_in, degc, epos);
    k_scan1<<<SCAN_BLOCKS, 256, 0, stream>>>(degc, scanned, bsum);
    k_scan2<<<1, 1, 0, stream>>>(bsum, boff, rowst);
    k_scan3<<<(N_NODES + 255) / 256, 256, 0, stream>>>(degc, scanned, boff, rowst);
    k_fill<<<2048, 256, 0, stream>>>(esrc_in, edst_in, rowst, epos, esrc);

    for (int i = 0; i < L; ++i) {
        k_agg<<<N_NODES / 4, 256, 0, stream>>>(h, rowst, esrc, agg);
        k_sage<<<2048, 256, 0, stream>>>(h, agg, sWl + (size_t)i * C * C, sbl + (size_t)i * C,
                                         sWr + (size_t)i * C * C, sg + (size_t)i * C,
                                         sb + (size_t)i * C, h);
    }

    k_pool_partial<<<128, 256, 0, stream>>>(h, batch, part);
    k_pool_final<<<1, 1024, 0, stream>>>(part, pooled);
    k_head<<<1, 512, 0, stream>>>(pooled, W0, b0, g0, bn0, mW, mb, mg, mbn, hW, hb, out);
}

// Round 5
// 1253.535 us; speedup vs baseline: 2.1064x; 1.1720x over previous
//
#include <hip/hip_runtime.h>
#include <hip/hip_bf16.h>
#include <math.h>

#define N_NODES 100000
#define N_EDGES 3200000
#define N_GRAPHS 16
#define C 64
#define L 6
#define H 32
#define EPS 1e-5f

static const int SCAN_BLOCKS = (N_NODES + 1023) / 1024;  // 98

__device__ __forceinline__ float gelu_exact(float x) {
    return 0.5f * x * (1.0f + erff(x * 0.70710678118654752440f));
}

__device__ __forceinline__ float wave_sum64(float v) {
#pragma unroll
    for (int m = 32; m >= 1; m >>= 1) v += __shfl_xor(v, m, 64);
    return v;
}

// sum over aligned 32-lane subgroup (masks <=16 stay inside the subgroup)
__device__ __forceinline__ float sum32(float v) {
#pragma unroll
    for (int m = 16; m >= 1; m >>= 1) v += __shfl_xor(v, m, 64);
    return v;
}

__device__ __forceinline__ unsigned short f32_to_bf16_rne(float f) {
    unsigned int u = __float_as_uint(f);
    u = (u + 0x7FFFu + ((u >> 16) & 1u)) >> 16;
    return (unsigned short)u;
}

// accumulate 4 bf16 channels (packed in uint2) into a float4
#define ACC4(acc, u)                                      \
    {                                                     \
        acc.x += __uint_as_float((u).x << 16);            \
        acc.y += __uint_as_float((u).x & 0xFFFF0000u);    \
        acc.z += __uint_as_float((u).y << 16);            \
        acc.w += __uint_as_float((u).y & 0xFFFF0000u);    \
    }

// ---------------- CSR build ----------------
// Pass 1: count in-degree AND record each edge's position within its dst
// bucket. Agent-scope relaxed atomic: theory is that system-scope atomicAdd
// write-through to HBM caused k_count's 112MB WRITE_SIZE; agent scope should
// keep the counter in L2.

__global__ void k_count(const int* __restrict__ dst, int* __restrict__ degc,
                        int* __restrict__ epos) {
    int i = blockIdx.x * blockDim.x + threadIdx.x;
    int stride = gridDim.x * blockDim.x;
    for (int e = i; e < N_EDGES; e += stride) {
        int pos = __hip_atomic_fetch_add(&degc[dst[e]], 1, __ATOMIC_RELAXED,
                                         __HIP_MEMORY_SCOPE_AGENT);
        epos[e] = pos;
    }
}

__global__ __launch_bounds__(256) void k_scan1(const int* __restrict__ degc,
                                               int* __restrict__ scanned,
                                               int* __restrict__ bsum) {
    __shared__ int sc[2][256];
    int tid = threadIdx.x;
    int base = blockIdx.x * 1024 + tid * 4;
    int c0 = (base + 0 < N_NODES) ? degc[base + 0] : 0;
    int c1 = (base + 1 < N_NODES) ? degc[base + 1] : 0;
    int c2 = (base + 2 < N_NODES) ? degc[base + 2] : 0;
    int c3 = (base + 3 < N_NODES) ? degc[base + 3] : 0;
    int p0 = c0, p1 = p0 + c1, p2 = p1 + c2, p3 = p2 + c3;
    sc[0][tid] = p3;
    __syncthreads();
    int pb = 0;
    for (int offd = 1; offd < 256; offd <<= 1) {
        int v = sc[pb][tid];
        if (tid >= offd) v += sc[pb][tid - offd];
        sc[pb ^ 1][tid] = v;
        __syncthreads();
        pb ^= 1;
    }
    int incl = sc[pb][tid];
    int exth = incl - p3;
    if (base + 0 < N_NODES) scanned[base + 0] = exth + p0;
    if (base + 1 < N_NODES) scanned[base + 1] = exth + p1;
    if (base + 2 < N_NODES) scanned[base + 2] = exth + p2;
    if (base + 3 < N_NODES) scanned[base + 3] = exth + p3;
    if (tid == 255) bsum[blockIdx.x] = incl;
}

__global__ void k_scan2(const int* __restrict__ bsum, int* __restrict__ boff,
                        int* __restrict__ rowst) {
    int run = 0;
    for (int b = 0; b < SCAN_BLOCKS; ++b) { boff[b] = run; run += bsum[b]; }
    rowst[N_NODES] = run;  // == N_EDGES
}

__global__ void k_scan3(const int* __restrict__ degc, const int* __restrict__ scanned,
                        const int* __restrict__ boff, int* __restrict__ rowst) {
    int i = blockIdx.x * blockDim.x + threadIdx.x;
    if (i < N_NODES) rowst[i] = boff[i >> 10] + scanned[i] - degc[i];
}

__global__ void k_fill(const int* __restrict__ src, const int* __restrict__ dst,
                       const int* __restrict__ rowst, const int* __restrict__ epos,
                       int* __restrict__ esrc) {
    int i = blockIdx.x * blockDim.x + threadIdx.x;
    int stride = gridDim.x * blockDim.x;
    for (int e = i; e < N_EDGES; e += stride) {
        int d = dst[e];
        esrc[rowst[d] + epos[e]] = src[e];
    }
}

// x -> bf16 shadow of h
__global__ void k_cvt(const float* __restrict__ x, unsigned short* __restrict__ hbf) {
    int i = blockIdx.x * blockDim.x + threadIdx.x;
    int stride = gridDim.x * blockDim.x;
    for (int k = i; k < N_NODES * C / 4; k += stride) {
        float4 v = ((const float4*)x)[k];
        ushort4 o;
        o.x = f32_to_bf16_rne(v.x);
        o.y = f32_to_bf16_rne(v.y);
        o.z = f32_to_bf16_rne(v.z);
        o.w = f32_to_bf16_rne(v.w);
        ((ushort4*)hbf)[k] = o;
    }
}

// ---------------- per-layer: mean aggregation (bf16 gather via CSR) --------
// One wave per node. lane = (edge sub-index lane>>4) x (channel quad lane&15);
// each lane loads 4 bf16 channels (8B) -> 4 rows of 128B per vmem instruction,
// 16 edges in flight per iteration. f32 accumulation.

__global__ __launch_bounds__(256) void k_agg(const unsigned short* __restrict__ hbf,
                                             const int* __restrict__ rowst,
                                             const int* __restrict__ esrc,
                                             float* __restrict__ agg) {
    const uint2* __restrict__ hb2 = (const uint2*)hbf;
    int wave = threadIdx.x >> 6, lane = threadIdx.x & 63;
    int n = blockIdx.x * 4 + wave;
    if (n >= N_NODES) return;
    int s0 = rowst[n], s1 = rowst[n + 1];
    int esub = lane >> 4;    // 0..3 edge sub-index
    int cq = lane & 15;      // channel quad
    float4 accA = make_float4(0.f, 0.f, 0.f, 0.f);
    float4 accB = make_float4(0.f, 0.f, 0.f, 0.f);
    int j = s0;
    for (; j + 16 <= s1; j += 16) {
        int sA = esrc[j + 0 + esub];
        int sB = esrc[j + 4 + esub];
        int sC = esrc[j + 8 + esub];
        int sD = esrc[j + 12 + esub];
        uint2 a = hb2[sA * 16 + cq];
        uint2 b = hb2[sB * 16 + cq];
        uint2 c = hb2[sC * 16 + cq];
        uint2 d = hb2[sD * 16 + cq];
        ACC4(accA, a);
        ACC4(accB, b);
        ACC4(accA, c);
        ACC4(accB, d);
    }
    for (; j + 4 <= s1; j += 4) {
        int s = esrc[j + esub];
        uint2 a = hb2[s * 16 + cq];
        ACC4(accA, a);
    }
    if (j < s1) {  // 1..3 leftover edges, predicated
        int jj = j + esub;
        bool v = jj < s1;
        int s = v ? esrc[jj] : 0;
        uint2 a = hb2[s * 16 + cq];
        if (!v) { a.x = 0; a.y = 0; }
        ACC4(accB, a);
    }
    accA.x += accB.x; accA.y += accB.y; accA.z += accB.z; accA.w += accB.w;
    // reduce across the 4 edge sub-groups (lanes differing in bits 4,5)
#pragma unroll
    for (int m = 16; m <= 32; m <<= 1) {
        accA.x += __shfl_xor(accA.x, m, 64);
        accA.y += __shfl_xor(accA.y, m, 64);
        accA.z += __shfl_xor(accA.z, m, 64);
        accA.w += __shfl_xor(accA.w, m, 64);
    }
    int cnt = s1 - s0;
    float inv = 1.0f / (float)max(cnt, 1);
    if (lane < 16) {
        float4 r = make_float4(accA.x * inv, accA.y * inv, accA.z * inv, accA.w * inv);
        ((float4*)agg)[(size_t)n * 16 + lane] = r;
    }
}

// ---------------- per-layer: fused GEMM+GELU+LN+residual ----------------
// One wave per node, BOTH GEMMs in-wave (Wl+Wr columns in 128 VGPRs),
// wave-private LDS rows, no block barriers. Also writes the bf16 shadow.

__global__ __launch_bounds__(256) void k_sage(const float* __restrict__ h,
                                              const float* __restrict__ agg,
                                              const float* __restrict__ Wl,
                                              const float* __restrict__ bl,
                                              const float* __restrict__ Wr,
                                              const float* __restrict__ gn,
                                              const float* __restrict__ bn,
                                              float* __restrict__ hout,
                                              unsigned short* __restrict__ hbf) {
    __shared__ float rowA[4][C];
    __shared__ float rowH[4][C];
    int lane = threadIdx.x & 63;
    int wave = threadIdx.x >> 6;
    float wl[C], wr[C];
#pragma unroll
    for (int j = 0; j < C; ++j) wl[j] = Wl[j * C + lane];  // column `lane`
#pragma unroll
    for (int j = 0; j < C; ++j) wr[j] = Wr[j * C + lane];
    float blc = bl[lane], gc = gn[lane], bc = bn[lane];

    const float4* a4 = (const float4*)rowA[wave];
    const float4* h4s = (const float4*)rowH[wave];
    for (int n = blockIdx.x * 4 + wave; n < N_NODES; n += 2048 * 4) {
        float av = agg[(size_t)n * C + lane];
        float hv = h[(size_t)n * C + lane];
        rowA[wave][lane] = av;
        rowH[wave][lane] = hv;
        float acc = blc;
#pragma unroll
        for (int k4 = 0; k4 < C / 4; ++k4) {
            float4 a = a4[k4];
            float4 b = h4s[k4];
            acc += a.x * wl[4 * k4 + 0] + a.y * wl[4 * k4 + 1] +
                   a.z * wl[4 * k4 + 2] + a.w * wl[4 * k4 + 3];
            acc += b.x * wr[4 * k4 + 0] + b.y * wr[4 * k4 + 1] +
                   b.z * wr[4 * k4 + 2] + b.w * wr[4 * k4 + 3];
        }
        float f = gelu_exact(acc);
        float mu = wave_sum64(f) * (1.0f / C);
        float d = f - mu;
        float var = wave_sum64(d * d) * (1.0f / C);
        float y = d * rsqrtf(var + EPS) * gc + bc;
        float res = y + hv;  // residual
        hout[(size_t)n * C + lane] = res;
        hbf[(size_t)n * C + lane] = f32_to_bf16_rne(res);
    }
}

// ---------------- pooling (segment_max) ----------------

__global__ __launch_bounds__(256) void k_pool_partial(const float* __restrict__ h,
                                                      const int* __restrict__ batch,
                                                      float* __restrict__ partial) {
    __shared__ float pp[4][N_GRAPHS][C];
    int lane = threadIdx.x & 63, wave = threadIdx.x >> 6;
#pragma unroll
    for (int g = 0; g < N_GRAPHS; ++g) pp[wave][g][lane] = -INFINITY;
    int chunk = (N_NODES + gridDim.x - 1) / gridDim.x;
    int start = blockIdx.x * chunk;
    int end = min(start + chunk, N_NODES);
    for (int n = start + wave; n < end; n += 4) {
        int g = batch[n];
        float v = h[(size_t)n * C + lane];
        pp[wave][g][lane] = fmaxf(pp[wave][g][lane], v);
    }
    __syncthreads();
    for (int g = wave * 4; g < wave * 4 + 4; ++g) {
        float m = fmaxf(fmaxf(pp[0][g][lane], pp[1][g][lane]),
                        fmaxf(pp[2][g][lane], pp[3][g][lane]));
        partial[(size_t)blockIdx.x * (N_GRAPHS * C) + g * C + lane] = m;
    }
}

__global__ void k_pool_final(const float* __restrict__ partial, float* __restrict__ pooled) {
    int t = threadIdx.x;  // 1024 threads = 16*64
    float m = -INFINITY;
    for (int b = 0; b < 128; ++b) m = fmaxf(m, partial[b * (N_GRAPHS * C) + t]);
    pooled[t] = m;
}

// ---------------- MLP head ----------------

__global__ __launch_bounds__(512) void k_head(const float* __restrict__ pooled,
                                              const float* __restrict__ W0,
                                              const float* __restrict__ b0,
                                              const float* __restrict__ g0,
                                              const float* __restrict__ bn0,
                                              const float* __restrict__ W,
                                              const float* __restrict__ bb,
                                              const float* __restrict__ gg,
                                              const float* __restrict__ bnn,
                                              const float* __restrict__ hW,
                                              const float* __restrict__ hb,
                                              float* __restrict__ out) {
    __shared__ float ps[N_GRAPHS][C];
    __shared__ float zs[N_GRAPHS][H];
    int t = threadIdx.x;
    for (int i = t; i < N_GRAPHS * C; i += 512) ps[i >> 6][i & 63] = pooled[i];
    __syncthreads();
    int g = t >> 5, j = t & 31;
    float acc = b0[j];
#pragma unroll 8
    for (int k = 0; k < C; ++k) acc += ps[g][k] * W0[k * H + j];
    acc = gelu_exact(acc);
    float mu = sum32(acc) * (1.0f / H);
    float d = acc - mu;
    float var = sum32(d * d) * (1.0f / H);
    float z = d * rsqrtf(var + EPS) * g0[j] + bn0[j];
    zs[g][j] = z;
    __syncthreads();
    for (int i = 0; i < 3; ++i) {
        float a = bb[i * H + j];
#pragma unroll 8
        for (int k = 0; k < H; ++k) a += zs[g][k] * W[i * H * H + k * H + j];
        a = gelu_exact(a);
        float mu2 = sum32(a) * (1.0f / H);
        float d2 = a - mu2;
        float v2 = sum32(d2 * d2) * (1.0f / H);
        float tt = d2 * rsqrtf(v2 + EPS) * gg[i * H + j] + bnn[i * H + j];
        float zn = tt + zs[g][j];
        __syncthreads();
        zs[g][j] = zn;
        __syncthreads();
    }
    float hv = zs[g][j] * hW[j];
    hv = sum32(hv);
    if (j == 0) out[g] = hv + hb[0];
}

// ---------------- launch ----------------

extern "C" void kernel_launch(void* const* d_in, const int* in_sizes, int n_in,
                              void* d_out, int out_size, void* d_ws, size_t ws_size,
                              hipStream_t stream) {
    const float* x    = (const float*)d_in[0];
    const int* edge   = (const int*)d_in[1];
    const int* batch  = (const int*)d_in[2];
    const float* sWl  = (const float*)d_in[3];
    const float* sbl  = (const float*)d_in[4];
    const float* sWr  = (const float*)d_in[5];
    const float* sg   = (const float*)d_in[6];
    const float* sb   = (const float*)d_in[7];
    const float* W0   = (const float*)d_in[8];
    const float* b0   = (const float*)d_in[9];
    const float* g0   = (const float*)d_in[10];
    const float* bn0  = (const float*)d_in[11];
    const float* mW   = (const float*)d_in[12];
    const float* mb   = (const float*)d_in[13];
    const float* mg   = (const float*)d_in[14];
    const float* mbn  = (const float*)d_in[15];
    const float* hW   = (const float*)d_in[16];
    const float* hb   = (const float*)d_in[17];
    float* out = (float*)d_out;

    const int* esrc_in = edge;            // edge_index[0]
    const int* edst_in = edge + N_EDGES;  // edge_index[1]

    char* ws = (char*)d_ws;
    size_t off = 0;
    auto alloc = [&](size_t bytes) {
        void* p = ws + off;
        off = (off + bytes + 1023) & ~(size_t)1023;
        return p;
    };
    float* h      = (float*)alloc((size_t)N_NODES * C * 4);
    float* agg    = (float*)alloc((size_t)N_NODES * C * 4);
    unsigned short* hbf = (unsigned short*)alloc((size_t)N_NODES * C * 2);
    int* degc     = (int*)alloc((size_t)N_NODES * 4);
    int* scanned  = (int*)alloc((size_t)N_NODES * 4);
    int* rowst    = (int*)alloc((size_t)(N_NODES + 1) * 4);
    int* esrc     = (int*)alloc((size_t)N_EDGES * 4);
    int* epos     = (int*)alloc((size_t)N_EDGES * 4);
    int* bsum     = (int*)alloc(128 * 4);
    int* boff     = (int*)alloc(128 * 4);
    float* part   = (float*)alloc((size_t)128 * N_GRAPHS * C * 4);
    float* pooled = (float*)alloc((size_t)N_GRAPHS * C * 4);
    (void)ws_size;

    hipMemsetAsync(degc, 0, (size_t)N_NODES * 4, stream);
    hipMemcpyAsync(h, x, (size_t)N_NODES * C * 4, hipMemcpyDeviceToDevice, stream);

    k_count<<<2048, 256, 0, stream>>>(edst_in, degc, epos);
    k_cvt<<<1600, 256, 0, stream>>>(x, hbf);
    k_scan1<<<SCAN_BLOCKS, 256, 0, stream>>>(degc, scanned, bsum);
    k_scan2<<<1, 1, 0, stream>>>(bsum, boff, rowst);
    k_scan3<<<(N_NODES + 255) / 256, 256, 0, stream>>>(degc, scanned, boff, rowst);
    k_fill<<<2048, 256, 0, stream>>>(esrc_in, edst_in, rowst, epos, esrc);

    for (int i = 0; i < L; ++i) {
        k_agg<<<N_NODES / 4, 256, 0, stream>>>(hbf, rowst, esrc, agg);
        k_sage<<<2048, 256, 0, stream>>>(h, agg, sWl + (size_t)i * C * C, sbl + (size_t)i * C,
                                         sWr + (size_t)i * C * C, sg + (size_t)i * C,
                                         sb + (size_t)i * C, h, hbf);
    }

    k_pool_partial<<<128, 256, 0, stream>>>(h, batch, part);
    k_pool_final<<<1, 1024, 0, stream>>>(part, pooled);
    k_head<<<1, 512, 0, stream>>>(pooled, W0, b0, g0, bn0, mW, mb, mg, mbn, hW, hb, out);
}

// Round 8
// 1230.569 us; speedup vs baseline: 2.1457x; 1.0187x over previous
//
#include <hip/hip_runtime.h>
#include <hip/hip_bf16.h>
#include <math.h>

#define N_NODES 100000
#define N_EDGES 3200000
#define N_GRAPHS 16
#define C 64
#define L 6
#define H 32
#define EPS 1e-5f
#define NPARTS 4
#define PART_DIV 25000
#define NBUCKETS (N_NODES * NPARTS)  // 400000

static const int SCAN_BLOCKS = (NBUCKETS + 1023) / 1024;  // 391

__device__ __forceinline__ float gelu_exact(float x) {
    return 0.5f * x * (1.0f + erff(x * 0.70710678118654752440f));
}

__device__ __forceinline__ float wave_sum64(float v) {
#pragma unroll
    for (int m = 32; m >= 1; m >>= 1) v += __shfl_xor(v, m, 64);
    return v;
}

// sum over aligned 32-lane subgroup (masks <=16 stay inside the subgroup)
__device__ __forceinline__ float sum32(float v) {
#pragma unroll
    for (int m = 16; m >= 1; m >>= 1) v += __shfl_xor(v, m, 64);
    return v;
}

__device__ __forceinline__ unsigned short f32_to_bf16_rne(float f) {
    unsigned int u = __float_as_uint(f);
    u = (u + 0x7FFFu + ((u >> 16) & 1u)) >> 16;
    return (unsigned short)u;
}

// accumulate 4 bf16 channels (packed in uint2) into a float4
#define ACC4(acc, u)                                      \
    {                                                     \
        acc.x += __uint_as_float((u).x << 16);            \
        acc.y += __uint_as_float((u).x & 0xFFFF0000u);    \
        acc.z += __uint_as_float((u).y << 16);            \
        acc.w += __uint_as_float((u).y & 0xFFFF0000u);    \
    }

// ---------------- CSR build (sub-bucketed by src partition) ----------------
// Bucket index = dst*4 + src/25000. Within each node, edges end up grouped by
// ascending src range -> all concurrent k_agg waves sweep the same 3.2MB
// src slice at roughly the same time (L2-resident gather).

__global__ void k_count(const int* __restrict__ src, const int* __restrict__ dst,
                        int* __restrict__ degc, int* __restrict__ epos) {
    int i = blockIdx.x * blockDim.x + threadIdx.x;
    int stride = gridDim.x * blockDim.x;
    for (int e = i; e < N_EDGES; e += stride) {
        int part = src[e] / PART_DIV;
        int pos = __hip_atomic_fetch_add(&degc[dst[e] * NPARTS + part], 1,
                                         __ATOMIC_RELAXED, __HIP_MEMORY_SCOPE_AGENT);
        epos[e] = pos;
    }
}

__global__ __launch_bounds__(256) void k_scan1(const int* __restrict__ degc,
                                               int* __restrict__ scanned,
                                               int* __restrict__ bsum) {
    __shared__ int sc[2][256];
    int tid = threadIdx.x;
    int base = blockIdx.x * 1024 + tid * 4;
    int c0 = (base + 0 < NBUCKETS) ? degc[base + 0] : 0;
    int c1 = (base + 1 < NBUCKETS) ? degc[base + 1] : 0;
    int c2 = (base + 2 < NBUCKETS) ? degc[base + 2] : 0;
    int c3 = (base + 3 < NBUCKETS) ? degc[base + 3] : 0;
    int p0 = c0, p1 = p0 + c1, p2 = p1 + c2, p3 = p2 + c3;
    sc[0][tid] = p3;
    __syncthreads();
    int pb = 0;
    for (int offd = 1; offd < 256; offd <<= 1) {
        int v = sc[pb][tid];
        if (tid >= offd) v += sc[pb][tid - offd];
        sc[pb ^ 1][tid] = v;
        __syncthreads();
        pb ^= 1;
    }
    int incl = sc[pb][tid];
    int exth = incl - p3;
    if (base + 0 < NBUCKETS) scanned[base + 0] = exth + p0;
    if (base + 1 < NBUCKETS) scanned[base + 1] = exth + p1;
    if (base + 2 < NBUCKETS) scanned[base + 2] = exth + p2;
    if (base + 3 < NBUCKETS) scanned[base + 3] = exth + p3;
    if (tid == 255) bsum[blockIdx.x] = incl;
}

__global__ void k_scan2(const int* __restrict__ bsum, int* __restrict__ boff,
                        int* __restrict__ rowst) {
    int run = 0;
    for (int b = 0; b < SCAN_BLOCKS; ++b) { boff[b] = run; run += bsum[b]; }
    rowst[NBUCKETS] = run;  // == N_EDGES
}

__global__ void k_scan3(const int* __restrict__ degc, const int* __restrict__ scanned,
                        const int* __restrict__ boff, int* __restrict__ rowst) {
    int i = blockIdx.x * blockDim.x + threadIdx.x;
    if (i < NBUCKETS) rowst[i] = boff[i >> 10] + scanned[i] - degc[i];
}

__global__ void k_fill(const int* __restrict__ src, const int* __restrict__ dst,
                       const int* __restrict__ rowst, const int* __restrict__ epos,
                       int* __restrict__ esrc) {
    int i = blockIdx.x * blockDim.x + threadIdx.x;
    int stride = gridDim.x * blockDim.x;
    for (int e = i; e < N_EDGES; e += stride) {
        int s = src[e];
        int part = s / PART_DIV;
        esrc[rowst[dst[e] * NPARTS + part] + epos[e]] = s;
    }
}

// x -> bf16 shadow of h
__global__ void k_cvt(const float* __restrict__ x, unsigned short* __restrict__ hbf) {
    int i = blockIdx.x * blockDim.x + threadIdx.x;
    int stride = gridDim.x * blockDim.x;
    for (int k = i; k < N_NODES * C / 4; k += stride) {
        float4 v = ((const float4*)x)[k];
        ushort4 o;
        o.x = f32_to_bf16_rne(v.x);
        o.y = f32_to_bf16_rne(v.y);
        o.z = f32_to_bf16_rne(v.z);
        o.w = f32_to_bf16_rne(v.w);
        ((ushort4*)hbf)[k] = o;
    }
}

// ---------------- per-layer: mean aggregation (bf16 gather via CSR) --------
// One wave per node; node n's edges are contiguous at rowst[4n]..rowst[4n+4].
// lane = (edge sub-index lane>>4) x (channel quad lane&15); 8B/lane loads,
// 16 edges in flight per iteration, f32 accumulation.

__global__ __launch_bounds__(256) void k_agg(const unsigned short* __restrict__ hbf,
                                             const int* __restrict__ rowst,
                                             const int* __restrict__ esrc,
                                             float* __restrict__ agg) {
    const uint2* __restrict__ hb2 = (const uint2*)hbf;
    int wave = threadIdx.x >> 6, lane = threadIdx.x & 63;
    int n = blockIdx.x * 4 + wave;
    if (n >= N_NODES) return;
    int s0 = rowst[n * NPARTS], s1 = rowst[n * NPARTS + NPARTS];
    int esub = lane >> 4;    // 0..3 edge sub-index
    int cq = lane & 15;      // channel quad
    float4 accA = make_float4(0.f, 0.f, 0.f, 0.f);
    float4 accB = make_float4(0.f, 0.f, 0.f, 0.f);
    int j = s0;
    for (; j + 16 <= s1; j += 16) {
        int sA = esrc[j + 0 + esub];
        int sB = esrc[j + 4 + esub];
        int sC = esrc[j + 8 + esub];
        int sD = esrc[j + 12 + esub];
        uint2 a = hb2[sA * 16 + cq];
        uint2 b = hb2[sB * 16 + cq];
        uint2 c = hb2[sC * 16 + cq];
        uint2 d = hb2[sD * 16 + cq];
        ACC4(accA, a);
        ACC4(accB, b);
        ACC4(accA, c);
        ACC4(accB, d);
    }
    for (; j + 4 <= s1; j += 4) {
        int s = esrc[j + esub];
        uint2 a = hb2[s * 16 + cq];
        ACC4(accA, a);
    }
    if (j < s1) {  // 1..3 leftover edges, predicated
        int jj = j + esub;
        bool v = jj < s1;
        int s = v ? esrc[jj] : 0;
        uint2 a = hb2[s * 16 + cq];
        if (!v) { a.x = 0; a.y = 0; }
        ACC4(accB, a);
    }
    accA.x += accB.x; accA.y += accB.y; accA.z += accB.z; accA.w += accB.w;
    // reduce across the 4 edge sub-groups (lanes differing in bits 4,5)
#pragma unroll
    for (int m = 16; m <= 32; m <<= 1) {
        accA.x += __shfl_xor(accA.x, m, 64);
        accA.y += __shfl_xor(accA.y, m, 64);
        accA.z += __shfl_xor(accA.z, m, 64);
        accA.w += __shfl_xor(accA.w, m, 64);
    }
    int cnt = s1 - s0;
    float inv = 1.0f / (float)max(cnt, 1);
    if (lane < 16) {
        float4 r = make_float4(accA.x * inv, accA.y * inv, accA.z * inv, accA.w * inv);
        ((float4*)agg)[(size_t)n * 16 + lane] = r;
    }
}

// ---------------- per-layer: fused GEMM+GELU+LN+residual ----------------
// One wave per node, BOTH GEMMs in-wave (Wl+Wr columns in 128 VGPRs),
// wave-private LDS rows, no block barriers. Also writes the bf16 shadow.

__global__ __launch_bounds__(256) void k_sage(const float* __restrict__ h,
                                              const float* __restrict__ agg,
                                              const float* __restrict__ Wl,
                                              const float* __restrict__ bl,
                                              const float* __restrict__ Wr,
                                              const float* __restrict__ gn,
                                              const float* __restrict__ bn,
                                              float* __restrict__ hout,
                                              unsigned short* __restrict__ hbf) {
    __shared__ float rowA[4][C];
    __shared__ float rowH[4][C];
    int lane = threadIdx.x & 63;
    int wave = threadIdx.x >> 6;
    float wl[C], wr[C];
#pragma unroll
    for (int j = 0; j < C; ++j) wl[j] = Wl[j * C + lane];  // column `lane`
#pragma unroll
    for (int j = 0; j < C; ++j) wr[j] = Wr[j * C + lane];
    float blc = bl[lane], gc = gn[lane], bc = bn[lane];

    const float4* a4 = (const float4*)rowA[wave];
    const float4* h4s = (const float4*)rowH[wave];
    for (int n = blockIdx.x * 4 + wave; n < N_NODES; n += 2048 * 4) {
        float av = agg[(size_t)n * C + lane];
        float hv = h[(size_t)n * C + lane];
        rowA[wave][lane] = av;
        rowH[wave][lane] = hv;
        float acc = blc;
#pragma unroll
        for (int k4 = 0; k4 < C / 4; ++k4) {
            float4 a = a4[k4];
            float4 b = h4s[k4];
            acc += a.x * wl[4 * k4 + 0] + a.y * wl[4 * k4 + 1] +
                   a.z * wl[4 * k4 + 2] + a.w * wl[4 * k4 + 3];
            acc += b.x * wr[4 * k4 + 0] + b.y * wr[4 * k4 + 1] +
                   b.z * wr[4 * k4 + 2] + b.w * wr[4 * k4 + 3];
        }
        float f = gelu_exact(acc);
        float mu = wave_sum64(f) * (1.0f / C);
        float d = f - mu;
        float var = wave_sum64(d * d) * (1.0f / C);
        float y = d * rsqrtf(var + EPS) * gc + bc;
        float res = y + hv;  // residual
        hout[(size_t)n * C + lane] = res;
        hbf[(size_t)n * C + lane] = f32_to_bf16_rne(res);
    }
}

// ---------------- pooling (segment_max) ----------------

__global__ __launch_bounds__(256) void k_pool_partial(const float* __restrict__ h,
                                                      const int* __restrict__ batch,
                                                      float* __restrict__ partial) {
    __shared__ float pp[4][N_GRAPHS][C];
    int lane = threadIdx.x & 63, wave = threadIdx.x >> 6;
#pragma unroll
    for (int g = 0; g < N_GRAPHS; ++g) pp[wave][g][lane] = -INFINITY;
    int chunk = (N_NODES + gridDim.x - 1) / gridDim.x;
    int start = blockIdx.x * chunk;
    int end = min(start + chunk, N_NODES);
    for (int n = start + wave; n < end; n += 4) {
        int g = batch[n];
        float v = h[(size_t)n * C + lane];
        pp[wave][g][lane] = fmaxf(pp[wave][g][lane], v);
    }
    __syncthreads();
    for (int g = wave * 4; g < wave * 4 + 4; ++g) {
        float m = fmaxf(fmaxf(pp[0][g][lane], pp[1][g][lane]),
                        fmaxf(pp[2][g][lane], pp[3][g][lane]));
        partial[(size_t)blockIdx.x * (N_GRAPHS * C) + g * C + lane] = m;
    }
}

__global__ void k_pool_final(const float* __restrict__ partial, float* __restrict__ pooled) {
    int t = threadIdx.x;  // 1024 threads = 16*64
    float m = -INFINITY;
    for (int b = 0; b < 128; ++b) m = fmaxf(m, partial[b * (N_GRAPHS * C) + t]);
    pooled[t] = m;
}

// ---------------- MLP head ----------------

__global__ __launch_bounds__(512) void k_head(const float* __restrict__ pooled,
                                              const float* __restrict__ W0,
                                              const float* __restrict__ b0,
                                              const float* __restrict__ g0,
                                              const float* __restrict__ bn0,
                                              const float* __restrict__ W,
                                              const float* __restrict__ bb,
                                              const float* __restrict__ gg,
                                              const float* __restrict__ bnn,
                                              const float* __restrict__ hW,
                                              const float* __restrict__ hb,
                                              float* __restrict__ out) {
    __shared__ float ps[N_GRAPHS][C];
    __shared__ float zs[N_GRAPHS][H];
    int t = threadIdx.x;
    for (int i = t; i < N_GRAPHS * C; i += 512) ps[i >> 6][i & 63] = pooled[i];
    __syncthreads();
    int g = t >> 5, j = t & 31;
    float acc = b0[j];
#pragma unroll 8
    for (int k = 0; k < C; ++k) acc += ps[g][k] * W0[k * H + j];
    acc = gelu_exact(acc);
    float mu = sum32(acc) * (1.0f / H);
    float d = acc - mu;
    float var = sum32(d * d) * (1.0f / H);
    float z = d * rsqrtf(var + EPS) * g0[j] + bn0[j];
    zs[g][j] = z;
    __syncthreads();
    for (int i = 0; i < 3; ++i) {
        float a = bb[i * H + j];
#pragma unroll 8
        for (int k = 0; k < H; ++k) a += zs[g][k] * W[i * H * H + k * H + j];
        a = gelu_exact(a);
        float mu2 = sum32(a) * (1.0f / H);
        float d2 = a - mu2;
        float v2 = sum32(d2 * d2) * (1.0f / H);
        float tt = d2 * rsqrtf(v2 + EPS) * gg[i * H + j] + bnn[i * H + j];
        float zn = tt + zs[g][j];
        __syncthreads();
        zs[g][j] = zn;
        __syncthreads();
    }
    float hv = zs[g][j] * hW[j];
    hv = sum32(hv);
    if (j == 0) out[g] = hv + hb[0];
}

// ---------------- launch ----------------

extern "C" void kernel_launch(void* const* d_in, const int* in_sizes, int n_in,
                              void* d_out, int out_size, void* d_ws, size_t ws_size,
                              hipStream_t stream) {
    const float* x    = (const float*)d_in[0];
    const int* edge   = (const int*)d_in[1];
    const int* batch  = (const int*)d_in[2];
    const float* sWl  = (const float*)d_in[3];
    const float* sbl  = (const float*)d_in[4];
    const float* sWr  = (const float*)d_in[5];
    const float* sg   = (const float*)d_in[6];
    const float* sb   = (const float*)d_in[7];
    const float* W0   = (const float*)d_in[8];
    const float* b0   = (const float*)d_in[9];
    const float* g0   = (const float*)d_in[10];
    const float* bn0  = (const float*)d_in[11];
    const float* mW   = (const float*)d_in[12];
    const float* mb   = (const float*)d_in[13];
    const float* mg   = (const float*)d_in[14];
    const float* mbn  = (const float*)d_in[15];
    const float* hW   = (const float*)d_in[16];
    const float* hb   = (const float*)d_in[17];
    float* out = (float*)d_out;

    const int* esrc_in = edge;            // edge_index[0]
    const int* edst_in = edge + N_EDGES;  // edge_index[1]

    char* ws = (char*)d_ws;
    size_t off = 0;
    auto alloc = [&](size_t bytes) {
        void* p = ws + off;
        off = (off + bytes + 1023) & ~(size_t)1023;
        return p;
    };
    float* h      = (float*)alloc((size_t)N_NODES * C * 4);
    float* agg    = (float*)alloc((size_t)N_NODES * C * 4);
    unsigned short* hbf = (unsigned short*)alloc((size_t)N_NODES * C * 2);
    int* degc     = (int*)alloc((size_t)NBUCKETS * 4);
    int* scanned  = (int*)alloc((size_t)NBUCKETS * 4);
    int* rowst    = (int*)alloc((size_t)(NBUCKETS + 1) * 4);
    int* esrc     = (int*)alloc((size_t)N_EDGES * 4);
    int* epos     = (int*)alloc((size_t)N_EDGES * 4);
    int* bsum     = (int*)alloc(512 * 4);
    int* boff     = (int*)alloc(512 * 4);
    float* part   = (float*)alloc((size_t)128 * N_GRAPHS * C * 4);
    float* pooled = (float*)alloc((size_t)N_GRAPHS * C * 4);
    (void)ws_size;

    hipMemsetAsync(degc, 0, (size_t)NBUCKETS * 4, stream);

    k_count<<<2048, 256, 0, stream>>>(esrc_in, edst_in, degc, epos);
    k_cvt<<<1600, 256, 0, stream>>>(x, hbf);
    k_scan1<<<SCAN_BLOCKS, 256, 0, stream>>>(degc, scanned, bsum);
    k_scan2<<<1, 1, 0, stream>>>(bsum, boff, rowst);
    k_scan3<<<(NBUCKETS + 255) / 256, 256, 0, stream>>>(degc, scanned, boff, rowst);
    k_fill<<<2048, 256, 0, stream>>>(esrc_in, edst_in, rowst, epos, esrc);

    for (int i = 0; i < L; ++i) {
        k_agg<<<N_NODES / 4, 256, 0, stream>>>(hbf, rowst, esrc, agg);
        k_sage<<<2048, 256, 0, stream>>>(i == 0 ? x : h, agg,
                                         sWl + (size_t)i * C * C, sbl + (size_t)i * C,
                                         sWr + (size_t)i * C * C, sg + (size_t)i * C,
                                         sb + (size_t)i * C, h, hbf);
    }

    k_pool_partial<<<128, 256, 0, stream>>>(h, batch, part);
    k_pool_final<<<1, 1024, 0, stream>>>(part, pooled);
    k_head<<<1, 512, 0, stream>>>(pooled, W0, b0, g0, bn0, mW, mb, mg, mbn, hW, hb, out);
}

// Round 11
// 1199.111 us; speedup vs baseline: 2.2020x; 1.0262x over previous
//
#include <hip/hip_runtime.h>
#include <hip/hip_bf16.h>
#include <math.h>

#define N_NODES 100000
#define N_EDGES 3200000
#define N_GRAPHS 16
#define C 64
#define L 6
#define H 32
#define EPS 1e-5f
#define NPARTS 4
#define PART_DIV 25000
#define NBUCKETS (N_NODES * NPARTS)  // 400000

static const int SCAN_BLOCKS = (NBUCKETS + 1023) / 1024;  // 391

__device__ __forceinline__ float gelu_exact(float x) {
    return 0.5f * x * (1.0f + erff(x * 0.70710678118654752440f));
}

__device__ __forceinline__ float wave_sum64(float v) {
#pragma unroll
    for (int m = 32; m >= 1; m >>= 1) v += __shfl_xor(v, m, 64);
    return v;
}

// sum over aligned 32-lane subgroup (masks <=16 stay inside the subgroup)
__device__ __forceinline__ float sum32(float v) {
#pragma unroll
    for (int m = 16; m >= 1; m >>= 1) v += __shfl_xor(v, m, 64);
    return v;
}

__device__ __forceinline__ unsigned short f32_to_bf16_rne(float f) {
    unsigned int u = __float_as_uint(f);
    u = (u + 0x7FFFu + ((u >> 16) & 1u)) >> 16;
    return (unsigned short)u;
}

// accumulate 8 bf16 channels (packed in uint4) into two float4s
#define ACC8(a0, a1, u)                                   \
    {                                                     \
        a0.x += __uint_as_float((u).x << 16);             \
        a0.y += __uint_as_float((u).x & 0xFFFF0000u);     \
        a0.z += __uint_as_float((u).y << 16);             \
        a0.w += __uint_as_float((u).y & 0xFFFF0000u);     \
        a1.x += __uint_as_float((u).z << 16);             \
        a1.y += __uint_as_float((u).z & 0xFFFF0000u);     \
        a1.z += __uint_as_float((u).w << 16);             \
        a1.w += __uint_as_float((u).w & 0xFFFF0000u);     \
    }

// ---------------- CSR build (sub-bucketed by src partition) ----------------

__global__ void k_count(const int* __restrict__ src, const int* __restrict__ dst,
                        int* __restrict__ degc, int* __restrict__ epos) {
    int i = blockIdx.x * blockDim.x + threadIdx.x;
    int stride = gridDim.x * blockDim.x;
    for (int e = i; e < N_EDGES; e += stride) {
        int part = src[e] / PART_DIV;
        int pos = __hip_atomic_fetch_add(&degc[dst[e] * NPARTS + part], 1,
                                         __ATOMIC_RELAXED, __HIP_MEMORY_SCOPE_AGENT);
        epos[e] = pos;
    }
}

__global__ __launch_bounds__(256) void k_scan1(const int* __restrict__ degc,
                                               int* __restrict__ scanned,
                                               int* __restrict__ bsum) {
    __shared__ int sc[2][256];
    int tid = threadIdx.x;
    int base = blockIdx.x * 1024 + tid * 4;
    int c0 = (base + 0 < NBUCKETS) ? degc[base + 0] : 0;
    int c1 = (base + 1 < NBUCKETS) ? degc[base + 1] : 0;
    int c2 = (base + 2 < NBUCKETS) ? degc[base + 2] : 0;
    int c3 = (base + 3 < NBUCKETS) ? degc[base + 3] : 0;
    int p0 = c0, p1 = p0 + c1, p2 = p1 + c2, p3 = p2 + c3;
    sc[0][tid] = p3;
    __syncthreads();
    int pb = 0;
    for (int offd = 1; offd < 256; offd <<= 1) {
        int v = sc[pb][tid];
        if (tid >= offd) v += sc[pb][tid - offd];
        sc[pb ^ 1][tid] = v;
        __syncthreads();
        pb ^= 1;
    }
    int incl = sc[pb][tid];
    int exth = incl - p3;
    if (base + 0 < NBUCKETS) scanned[base + 0] = exth + p0;
    if (base + 1 < NBUCKETS) scanned[base + 1] = exth + p1;
    if (base + 2 < NBUCKETS) scanned[base + 2] = exth + p2;
    if (base + 3 < NBUCKETS) scanned[base + 3] = exth + p3;
    if (tid == 255) bsum[blockIdx.x] = incl;
}

__global__ void k_scan2(const int* __restrict__ bsum, int* __restrict__ boff,
                        int* __restrict__ rowst) {
    int run = 0;
    for (int b = 0; b < SCAN_BLOCKS; ++b) { boff[b] = run; run += bsum[b]; }
    rowst[NBUCKETS] = run;  // == N_EDGES
}

__global__ void k_scan3(const int* __restrict__ degc, const int* __restrict__ scanned,
                        const int* __restrict__ boff, int* __restrict__ rowst) {
    int i = blockIdx.x * blockDim.x + threadIdx.x;
    if (i < NBUCKETS) rowst[i] = boff[i >> 10] + scanned[i] - degc[i];
}

__global__ void k_fill(const int* __restrict__ src, const int* __restrict__ dst,
                       const int* __restrict__ rowst, const int* __restrict__ epos,
                       int* __restrict__ esrc) {
    int i = blockIdx.x * blockDim.x + threadIdx.x;
    int stride = gridDim.x * blockDim.x;
    for (int e = i; e < N_EDGES; e += stride) {
        int s = src[e];
        int part = s / PART_DIV;
        esrc[rowst[dst[e] * NPARTS + part] + epos[e]] = s;
    }
}

// x -> bf16 shadow of h
__global__ void k_cvt(const float* __restrict__ x, unsigned short* __restrict__ hbf) {
    int i = blockIdx.x * blockDim.x + threadIdx.x;
    int stride = gridDim.x * blockDim.x;
    for (int k = i; k < N_NODES * C / 4; k += stride) {
        float4 v = ((const float4*)x)[k];
        ushort4 o;
        o.x = f32_to_bf16_rne(v.x);
        o.y = f32_to_bf16_rne(v.y);
        o.z = f32_to_bf16_rne(v.z);
        o.w = f32_to_bf16_rne(v.w);
        ((ushort4*)hbf)[k] = o;
    }
}

// ---------------- per-layer: mean aggregation (bf16 gather via CSR) --------
// One wave per node. 16B/lane gathers: lane = (edge sub-index lane>>3) x
// (channel oct lane&7); 8 lanes cover a 128B row -> 8 rows per vmem
// instruction (2x the address-rate efficiency of 8B/lane). 32 edges per
// unrolled iteration, 4 gathers in flight, f32 accumulation.

__global__ __launch_bounds__(256) void k_agg(const unsigned short* __restrict__ hbf,
                                             const int* __restrict__ rowst,
                                             const int* __restrict__ esrc,
                                             float* __restrict__ agg) {
    const uint4* __restrict__ hb4 = (const uint4*)hbf;  // row n = hb4[n*8 + co]
    int wave = threadIdx.x >> 6, lane = threadIdx.x & 63;
    int n = blockIdx.x * 4 + wave;
    if (n >= N_NODES) return;
    int s0 = rowst[n * NPARTS], s1 = rowst[n * NPARTS + NPARTS];
    int esub = lane >> 3;   // 0..7 edge sub-index
    int co = lane & 7;      // channel oct (16B = 8 bf16)
    float4 accA0 = make_float4(0.f, 0.f, 0.f, 0.f), accA1 = accA0;
    float4 accB0 = accA0, accB1 = accA0;
    int j = s0;
    for (; j + 32 <= s1; j += 32) {
        int iA = esrc[j + 0 + esub];
        int iB = esrc[j + 8 + esub];
        int iC = esrc[j + 16 + esub];
        int iD = esrc[j + 24 + esub];
        uint4 a = hb4[(size_t)iA * 8 + co];
        uint4 b = hb4[(size_t)iB * 8 + co];
        uint4 c = hb4[(size_t)iC * 8 + co];
        uint4 d = hb4[(size_t)iD * 8 + co];
        ACC8(accA0, accA1, a);
        ACC8(accB0, accB1, b);
        ACC8(accA0, accA1, c);
        ACC8(accB0, accB1, d);
    }
    for (; j + 8 <= s1; j += 8) {
        int s = esrc[j + esub];
        uint4 a = hb4[(size_t)s * 8 + co];
        ACC8(accA0, accA1, a);
    }
    if (j < s1) {  // 1..7 leftover edges, predicated
        int jj = j + esub;
        bool v = jj < s1;
        int s = v ? esrc[jj] : 0;
        uint4 a = hb4[(size_t)s * 8 + co];
        if (!v) { a.x = 0; a.y = 0; a.z = 0; a.w = 0; }
        ACC8(accB0, accB1, a);
    }
    accA0.x += accB0.x; accA0.y += accB0.y; accA0.z += accB0.z; accA0.w += accB0.w;
    accA1.x += accB1.x; accA1.y += accB1.y; accA1.z += accB1.z; accA1.w += accB1.w;
    // reduce across the 8 edge sub-groups (lanes differing in bits 3,4,5)
#pragma unroll
    for (int m = 8; m <= 32; m <<= 1) {
        accA0.x += __shfl_xor(accA0.x, m, 64);
        accA0.y += __shfl_xor(accA0.y, m, 64);
        accA0.z += __shfl_xor(accA0.z, m, 64);
        accA0.w += __shfl_xor(accA0.w, m, 64);
        accA1.x += __shfl_xor(accA1.x, m, 64);
        accA1.y += __shfl_xor(accA1.y, m, 64);
        accA1.z += __shfl_xor(accA1.z, m, 64);
        accA1.w += __shfl_xor(accA1.w, m, 64);
    }
    int cnt = s1 - s0;
    float inv = 1.0f / (float)max(cnt, 1);
    if (lane < 8) {
        float4 r0 = make_float4(accA0.x * inv, accA0.y * inv, accA0.z * inv, accA0.w * inv);
        float4 r1 = make_float4(accA1.x * inv, accA1.y * inv, accA1.z * inv, accA1.w * inv);
        ((float4*)agg)[(size_t)n * 16 + co * 2 + 0] = r0;
        ((float4*)agg)[(size_t)n * 16 + co * 2 + 1] = r1;
    }
}

// ---------------- per-layer: fused GEMM+GELU+LN+residual ----------------
// One wave per node, BOTH GEMMs in-wave (Wl+Wr columns in 128 VGPRs),
// wave-private LDS rows, no block barriers. Also writes the bf16 shadow.

__global__ __launch_bounds__(256) void k_sage(const float* __restrict__ h,
                                              const float* __restrict__ agg,
                                              const float* __restrict__ Wl,
                                              const float* __restrict__ bl,
                                              const float* __restrict__ Wr,
                                              const float* __restrict__ gn,
                                              const float* __restrict__ bn,
                                              float* __restrict__ hout,
                                              unsigned short* __restrict__ hbf) {
    __shared__ float rowA[4][C];
    __shared__ float rowH[4][C];
    int lane = threadIdx.x & 63;
    int wave = threadIdx.x >> 6;
    float wl[C], wr[C];
#pragma unroll
    for (int j = 0; j < C; ++j) wl[j] = Wl[j * C + lane];  // column `lane`
#pragma unroll
    for (int j = 0; j < C; ++j) wr[j] = Wr[j * C + lane];
    float blc = bl[lane], gc = gn[lane], bc = bn[lane];

    const float4* a4 = (const float4*)rowA[wave];
    const float4* h4s = (const float4*)rowH[wave];
    for (int n = blockIdx.x * 4 + wave; n < N_NODES; n += 2048 * 4) {
        float av = agg[(size_t)n * C + lane];
        float hv = h[(size_t)n * C + lane];
        rowA[wave][lane] = av;
        rowH[wave][lane] = hv;
        float acc = blc;
#pragma unroll
        for (int k4 = 0; k4 < C / 4; ++k4) {
            float4 a = a4[k4];
            float4 b = h4s[k4];
            acc += a.x * wl[4 * k4 + 0] + a.y * wl[4 * k4 + 1] +
                   a.z * wl[4 * k4 + 2] + a.w * wl[4 * k4 + 3];
            acc += b.x * wr[4 * k4 + 0] + b.y * wr[4 * k4 + 1] +
                   b.z * wr[4 * k4 + 2] + b.w * wr[4 * k4 + 3];
        }
        float f = gelu_exact(acc);
        float mu = wave_sum64(f) * (1.0f / C);
        float d = f - mu;
        float var = wave_sum64(d * d) * (1.0f / C);
        float y = d * rsqrtf(var + EPS) * gc + bc;
        float res = y + hv;  // residual
        hout[(size_t)n * C + lane] = res;
        hbf[(size_t)n * C + lane] = f32_to_bf16_rne(res);
    }
}

// ---------------- pooling (segment_max) ----------------

__global__ __launch_bounds__(256) void k_pool_partial(const float* __restrict__ h,
                                                      const int* __restrict__ batch,
                                                      float* __restrict__ partial) {
    __shared__ float pp[4][N_GRAPHS][C];
    int lane = threadIdx.x & 63, wave = threadIdx.x >> 6;
#pragma unroll
    for (int g = 0; g < N_GRAPHS; ++g) pp[wave][g][lane] = -INFINITY;
    int chunk = (N_NODES + gridDim.x - 1) / gridDim.x;
    int start = blockIdx.x * chunk;
    int end = min(start + chunk, N_NODES);
    for (int n = start + wave; n < end; n += 4) {
        int g = batch[n];
        float v = h[(size_t)n * C + lane];
        pp[wave][g][lane] = fmaxf(pp[wave][g][lane], v);
    }
    __syncthreads();
    for (int g = wave * 4; g < wave * 4 + 4; ++g) {
        float m = fmaxf(fmaxf(pp[0][g][lane], pp[1][g][lane]),
                        fmaxf(pp[2][g][lane], pp[3][g][lane]));
        partial[(size_t)blockIdx.x * (N_GRAPHS * C) + g * C + lane] = m;
    }
}

__global__ void k_pool_final(const float* __restrict__ partial, float* __restrict__ pooled) {
    int t = threadIdx.x;  // 1024 threads = 16*64
    float m = -INFINITY;
    for (int b = 0; b < 128; ++b) m = fmaxf(m, partial[b * (N_GRAPHS * C) + t]);
    pooled[t] = m;
}

// ---------------- MLP head ----------------

__global__ __launch_bounds__(512) void k_head(const float* __restrict__ pooled,
                                              const float* __restrict__ W0,
                                              const float* __restrict__ b0,
                                              const float* __restrict__ g0,
                                              const float* __restrict__ bn0,
                                              const float* __restrict__ W,
                                              const float* __restrict__ bb,
                                              const float* __restrict__ gg,
                                              const float* __restrict__ bnn,
                                              const float* __restrict__ hW,
                                              const float* __restrict__ hb,
                                              float* __restrict__ out) {
    __shared__ float ps[N_GRAPHS][C];
    __shared__ float zs[N_GRAPHS][H];
    int t = threadIdx.x;
    for (int i = t; i < N_GRAPHS * C; i += 512) ps[i >> 6][i & 63] = pooled[i];
    __syncthreads();
    int g = t >> 5, j = t & 31;
    float acc = b0[j];
#pragma unroll 8
    for (int k = 0; k < C; ++k) acc += ps[g][k] * W0[k * H + j];
    acc = gelu_exact(acc);
    float mu = sum32(acc) * (1.0f / H);
    float d = acc - mu;
    float var = sum32(d * d) * (1.0f / H);
    float z = d * rsqrtf(var + EPS) * g0[j] + bn0[j];
    zs[g][j] = z;
    __syncthreads();
    for (int i = 0; i < 3; ++i) {
        float a = bb[i * H + j];
#pragma unroll 8
        for (int k = 0; k < H; ++k) a += zs[g][k] * W[i * H * H + k * H + j];
        a = gelu_exact(a);
        float mu2 = sum32(a) * (1.0f / H);
        float d2 = a - mu2;
        float v2 = sum32(d2 * d2) * (1.0f / H);
        float tt = d2 * rsqrtf(v2 + EPS) * gg[i * H + j] + bnn[i * H + j];
        float zn = tt + zs[g][j];
        __syncthreads();
        zs[g][j] = zn;
        __syncthreads();
    }
    float hv = zs[g][j] * hW[j];
    hv = sum32(hv);
    if (j == 0) out[g] = hv + hb[0];
}

// ---------------- launch ----------------

extern "C" void kernel_launch(void* const* d_in, const int* in_sizes, int n_in,
                              void* d_out, int out_size, void* d_ws, size_t ws_size,
                              hipStream_t stream) {
    const float* x    = (const float*)d_in[0];
    const int* edge   = (const int*)d_in[1];
    const int* batch  = (const int*)d_in[2];
    const float* sWl  = (const float*)d_in[3];
    const float* sbl  = (const float*)d_in[4];
    const float* sWr  = (const float*)d_in[5];
    const float* sg   = (const float*)d_in[6];
    const float* sb   = (const float*)d_in[7];
    const float* W0   = (const float*)d_in[8];
    const float* b0   = (const float*)d_in[9];
    const float* g0   = (const float*)d_in[10];
    const float* bn0  = (const float*)d_in[11];
    const float* mW   = (const float*)d_in[12];
    const float* mb   = (const float*)d_in[13];
    const float* mg   = (const float*)d_in[14];
    const float* mbn  = (const float*)d_in[15];
    const float* hW   = (const float*)d_in[16];
    const float* hb   = (const float*)d_in[17];
    float* out = (float*)d_out;

    const int* esrc_in = edge;            // edge_index[0]
    const int* edst_in = edge + N_EDGES;  // edge_index[1]

    char* ws = (char*)d_ws;
    size_t off = 0;
    auto alloc = [&](size_t bytes) {
        void* p = ws + off;
        off = (off + bytes + 1023) & ~(size_t)1023;
        return p;
    };
    float* h      = (float*)alloc((size_t)N_NODES * C * 4);
    float* agg    = (float*)alloc((size_t)N_NODES * C * 4);
    unsigned short* hbf = (unsigned short*)alloc((size_t)N_NODES * C * 2);
    int* degc     = (int*)alloc((size_t)NBUCKETS * 4);
    int* scanned  = (int*)alloc((size_t)NBUCKETS * 4);
    int* rowst    = (int*)alloc((size_t)(NBUCKETS + 1) * 4);
    int* esrc     = (int*)alloc((size_t)N_EDGES * 4);
    int* epos     = (int*)alloc((size_t)N_EDGES * 4);
    int* bsum     = (int*)alloc(512 * 4);
    int* boff     = (int*)alloc(512 * 4);
    float* part   = (float*)alloc((size_t)128 * N_GRAPHS * C * 4);
    float* pooled = (float*)alloc((size_t)N_GRAPHS * C * 4);
    (void)ws_size;

    hipMemsetAsync(degc, 0, (size_t)NBUCKETS * 4, stream);

    k_count<<<2048, 256, 0, stream>>>(esrc_in, edst_in, degc, epos);
    k_cvt<<<1600, 256, 0, stream>>>(x, hbf);
    k_scan1<<<SCAN_BLOCKS, 256, 0, stream>>>(degc, scanned, bsum);
    k_scan2<<<1, 1, 0, stream>>>(bsum, boff, rowst);
    k_scan3<<<(NBUCKETS + 255) / 256, 256, 0, stream>>>(degc, scanned, boff, rowst);
    k_fill<<<2048, 256, 0, stream>>>(esrc_in, edst_in, rowst, epos, esrc);

    for (int i = 0; i < L; ++i) {
        k_agg<<<N_NODES / 4, 256, 0, stream>>>(hbf, rowst, esrc, agg);
        k_sage<<<2048, 256, 0, stream>>>(i == 0 ? x : h, agg,
                                         sWl + (size_t)i * C * C, sbl + (size_t)i * C,
                                         sWr + (size_t)i * C * C, sg + (size_t)i * C,
                                         sb + (size_t)i * C, h, hbf);
    }

    k_pool_partial<<<128, 256, 0, stream>>>(h, batch, part);
    k_pool_final<<<1, 1024, 0, stream>>>(part, pooled);
    k_head<<<1, 512, 0, stream>>>(pooled, W0, b0, g0, bn0, mW, mb, mg, mbn, hW, hb, out);
}